// Round 13
// baseline (27.986 us; speedup 1.0000x reference)
//
#include <hip/hip_runtime.h>

// Problem constants (fixed by the reference setup)
#define BB 8
#define LL 4096
#define DD 1024
#define KK 2048

#define RPB 32              // output rows per block
#define TPB 512             // threads per block (8 waves)
#define NWORDS (LL / 64)    // 64 u64 words per batch bitmap

typedef float f32x4 __attribute__((ext_vector_type(4)));

// Fused kernel, 512 blocks x 512 threads (2 blocks/CU x 8 waves = 16 waves/CU).
// R12 structure (cached loads, NT stores, 2-barrier preamble) with DOUBLE
// per-thread batch depth: 16 loads issued back-to-back, then 16 NT stores.
// Per-CU in-flight bytes identical to R10/R12 (256 KB); tests whether coarser
// read/write phase alternation recovers DRAM turnaround losses.
//  1) bitmap: 8 coalesced dword loads + __ballot -> 64 u64 words in LDS,
//  2) wave 0: shfl prefix-scan of 64 popcounts; lanes 0-31 binary-search
//     their output row (k-th set bit if k < num_tokens else
//     (k-num_tokens)-th clear bit == stable compaction order of
//     argsort(i + (~bm)*L)[:K], unique keys) and write next_mask,
//  3) copy 32 rows x 4 KiB: 16 steps x 2 rows (tid>>8 = row half).
__global__ void __launch_bounds__(TPB)
fused_gather_kernel(const f32x4* __restrict__ src,
                    const int* __restrict__ bm,
                    f32x4* __restrict__ dst,
                    float* __restrict__ om) {
    __shared__ unsigned long long words[NWORDS];
    __shared__ int pre[NWORDS];     // popcounts, then inclusive prefix
    __shared__ int srows[RPB];

    const int blk   = blockIdx.x;          // 0 .. 511
    const int tid   = threadIdx.x;         // 0 .. 511
    const int lane  = tid & 63;
    const int wave  = tid >> 6;            // 0 .. 7
    const int b     = blk >> 6;            // 64 blocks per batch
    const int kbase = (blk & 63) * RPB;    // k offset within batch

    const int* m = bm + (size_t)b * LL;

    // 1) bitmap: ballot j in wave w covers positions (j*8+w)*64 + lane
#pragma unroll
    for (int j = 0; j < 8; ++j) {
        const unsigned long long w = __ballot(m[j * TPB + tid] != 0);
        if (lane == 0) {
            const int wi = j * 8 + wave;
            words[wi] = w;
            pre[wi]   = __popcll(w);
        }
    }
    __syncthreads();

    // 2) wave 0: scan + row-search + mask write (same-wave, lgkmcnt-ordered)
    if (wave == 0) {
        int v = pre[lane];
#pragma unroll
        for (int off = 1; off < 64; off <<= 1) {
            const int t = __shfl_up(v, off, 64);
            if (lane >= off) v += t;
        }
        pre[lane] = v;
        const int total = __shfl(v, 63, 64);   // num_tokens for batch b

        if (lane < RPB) {
            const int kb = kbase + lane;
            int lo = 0, hi = NWORDS - 1, r;
            unsigned long long x;
            if (kb < total) {
                // smallest word w with pre[w] > kb
                while (lo < hi) { const int mid = (lo + hi) >> 1; if (pre[mid] > kb) hi = mid; else lo = mid + 1; }
                r = kb - ((lo == 0) ? 0 : pre[lo - 1]);
                x = words[lo];
            } else {
                // clear-bit select: zeros_incl[w] = (w+1)*64 - pre[w]
                const int rz = kb - total;
                while (lo < hi) { const int mid = (lo + hi) >> 1; if ((mid + 1) * 64 - pre[mid] > rz) hi = mid; else lo = mid + 1; }
                r = rz - (lo * 64 - ((lo == 0) ? 0 : pre[lo - 1]));
                x = ~words[lo];
            }
            // select r-th (0-based) set bit of x
            int pos = 0;
#pragma unroll
            for (int sh = 32; sh >= 1; sh >>= 1) {
                const int c = __popcll(x & ((1ull << sh) - 1ull));
                if (r >= c) { r -= c; x >>= sh; pos += sh; }
            }
            srows[lane] = lo * 64 + pos;
            om[(size_t)b * KK + kb] = (kb < total) ? 1.0f : 0.0f;
        }
    }
    __syncthreads();

    // 3) copy: 16 steps x 2 rows (tid>>8 selects row half, tid&255 column)
    const int half = tid >> 8;             // 0 or 1
    const int col  = tid & 255;
    const size_t srcbase = (size_t)b * LL * (DD / 4);
    f32x4 v[16];
#pragma unroll
    for (int j = 0; j < 16; ++j)
        v[j] = src[srcbase + (size_t)srows[j * 2 + half] * (DD / 4) + col];
    f32x4* d = dst + ((size_t)b * KK + kbase + half) * (DD / 4) + col;
#pragma unroll
    for (int j = 0; j < 16; ++j)
        __builtin_nontemporal_store(v[j], &d[(size_t)(j * 2) * (DD / 4)]);
}

extern "C" void kernel_launch(void* const* d_in, const int* in_sizes, int n_in,
                              void* d_out, int out_size, void* d_ws, size_t ws_size,
                              hipStream_t stream) {
    const float* hs = (const float*)d_in[0];   // (B, L, D) f32
    const int*   bm = (const int*)d_in[1];     // (B, L) bool -> int32
    // d_in[2] (mask) unused; d_in[3] (next_max_seqlen) fixed at K=2048

    float* out_hs   = (float*)d_out;                        // B*K*D floats
    float* out_mask = (float*)d_out + (size_t)BB * KK * DD; // B*K floats

    fused_gather_kernel<<<(BB * KK) / RPB, TPB, 0, stream>>>(
        (const f32x4*)hs, bm, (f32x4*)out_hs, out_mask);
}

// Round 14
// 27.227 us; speedup vs baseline: 1.0279x; 1.0279x over previous
//
#include <hip/hip_runtime.h>

// Problem constants (fixed by the reference setup)
#define BB 8
#define LL 4096
#define DD 1024
#define KK 2048

#define RPB 32              // output rows per block
#define TPB 1024            // threads per block (16 waves)
#define NWORDS (LL / 64)    // 64 u64 words per batch bitmap

typedef float f32x4 __attribute__((ext_vector_type(4)));

// Fused kernel, 512 blocks x 1024 threads (2 blocks/CU x 16 waves = 32 waves/CU).
// BEST configuration (R12, 27.28 us): cached loads, NT stores, 2-barrier
// preamble, 8-deep copy batches, 32 waves/CU.
//  1) bitmap: 4 coalesced dword loads + __ballot -> 64 u64 words in LDS,
//  2) wave 0: shfl prefix-scan of 64 popcounts -> pre[]; lanes 0-31 then
//     binary-search their output row (k-th set bit if k < num_tokens else
//     (k-num_tokens)-th clear bit == stable compaction order of
//     argsort(i + (~bm)*L)[:K], unique keys) and write next_mask,
//  3) copy 32 rows x 4 KiB (8 steps x 4 rows; cached loads, NT stores).
__global__ void __launch_bounds__(TPB)
fused_gather_kernel(const f32x4* __restrict__ src,
                    const int* __restrict__ bm,
                    f32x4* __restrict__ dst,
                    float* __restrict__ om) {
    __shared__ unsigned long long words[NWORDS];
    __shared__ int pre[NWORDS];     // popcounts, then inclusive prefix
    __shared__ int srows[RPB];

    const int blk   = blockIdx.x;          // 0 .. 511
    const int tid   = threadIdx.x;         // 0 .. 1023
    const int lane  = tid & 63;
    const int wave  = tid >> 6;            // 0 .. 15
    const int b     = blk >> 6;            // 64 blocks per batch
    const int kbase = (blk & 63) * RPB;    // k offset within batch

    const int* m = bm + (size_t)b * LL;

    // 1) bitmap: ballot j in wave w covers positions (j*16+w)*64 + lane
#pragma unroll
    for (int j = 0; j < 4; ++j) {
        const unsigned long long w = __ballot(m[j * TPB + tid] != 0);
        if (lane == 0) {
            const int wi = j * 16 + wave;
            words[wi] = w;
            pre[wi]   = __popcll(w);
        }
    }
    __syncthreads();

    // 2) wave 0: scan + row-search + mask write (no intermediate barrier;
    //    pre[] read-after-write within the same wave is lgkmcnt-ordered)
    if (wave == 0) {
        int v = pre[lane];
#pragma unroll
        for (int off = 1; off < 64; off <<= 1) {
            const int t = __shfl_up(v, off, 64);
            if (lane >= off) v += t;
        }
        pre[lane] = v;
        const int total = __shfl(v, 63, 64);   // num_tokens for batch b

        if (lane < RPB) {
            const int kb = kbase + lane;
            int lo = 0, hi = NWORDS - 1, r;
            unsigned long long x;
            if (kb < total) {
                // smallest word w with pre[w] > kb
                while (lo < hi) { const int mid = (lo + hi) >> 1; if (pre[mid] > kb) hi = mid; else lo = mid + 1; }
                r = kb - ((lo == 0) ? 0 : pre[lo - 1]);
                x = words[lo];
            } else {
                // clear-bit select: zeros_incl[w] = (w+1)*64 - pre[w]
                const int rz = kb - total;
                while (lo < hi) { const int mid = (lo + hi) >> 1; if ((mid + 1) * 64 - pre[mid] > rz) hi = mid; else lo = mid + 1; }
                r = rz - (lo * 64 - ((lo == 0) ? 0 : pre[lo - 1]));
                x = ~words[lo];
            }
            // select r-th (0-based) set bit of x
            int pos = 0;
#pragma unroll
            for (int sh = 32; sh >= 1; sh >>= 1) {
                const int c = __popcll(x & ((1ull << sh) - 1ull));
                if (r >= c) { r -= c; x >>= sh; pos += sh; }
            }
            srows[lane] = lo * 64 + pos;
            om[(size_t)b * KK + kb] = (kb < total) ? 1.0f : 0.0f;
        }
    }
    __syncthreads();

    // 3) copy: 8 steps x 4 rows (tid>>8 selects row quarter, tid&255 column)
    const int quarter = tid >> 8;          // 0 .. 3
    const int col     = tid & 255;
    const size_t srcbase = (size_t)b * LL * (DD / 4);
    f32x4 v[8];
#pragma unroll
    for (int j = 0; j < 8; ++j)
        v[j] = src[srcbase + (size_t)srows[j * 4 + quarter] * (DD / 4) + col];
    f32x4* d = dst + ((size_t)b * KK + kbase + quarter) * (DD / 4) + col;
#pragma unroll
    for (int j = 0; j < 8; ++j)
        __builtin_nontemporal_store(v[j], &d[(size_t)(j * 4) * (DD / 4)]);
}

extern "C" void kernel_launch(void* const* d_in, const int* in_sizes, int n_in,
                              void* d_out, int out_size, void* d_ws, size_t ws_size,
                              hipStream_t stream) {
    const float* hs = (const float*)d_in[0];   // (B, L, D) f32
    const int*   bm = (const int*)d_in[1];     // (B, L) bool -> int32
    // d_in[2] (mask) unused; d_in[3] (next_max_seqlen) fixed at K=2048

    float* out_hs   = (float*)d_out;                        // B*K*D floats
    float* out_mask = (float*)d_out + (size_t)BB * KK * DD; // B*K floats

    fused_gather_kernel<<<(BB * KK) / RPB, TPB, 0, stream>>>(
        (const f32x4*)hs, bm, (f32x4*)out_hs, out_mask);
}